// Round 10
// baseline (127.758 us; speedup 1.0000x reference)
//
#include <hip/hip_runtime.h>
#include <hip/hip_bf16.h>
#include <math.h>

#define T_ 1024
#define H_ 1024
#define E_ 16
#define I_ 512
#define KSEL 4
#define IS_ 1024

typedef unsigned short u16;
typedef __attribute__((ext_vector_type(8))) short short8;
typedef __attribute__((ext_vector_type(4))) float f32x4;

__device__ __forceinline__ u16 f2bf(float f) {
    union { float f; unsigned int u; } v; v.f = f;
    unsigned int u = v.u;
    return (u16)((u + 0x7fffu + ((u >> 16) & 1u)) >> 16);
}
__device__ __forceinline__ float bf2f(u16 b) {
    union { unsigned int u; float f; } v; v.u = ((unsigned int)b) << 16;
    return v.f;
}
__device__ __forceinline__ void gload16(const u16* g, u16* l) {
    __builtin_amdgcn_global_load_lds(
        (const __attribute__((address_space(1))) void*)g,
        (__attribute__((address_space(3))) void*)l, 16, 0, 0);
}

// ------ router: 1 block/token; emits x_bf row, per-expert lists, dense weights ------
__global__ __launch_bounds__(256)
void router_kernel(const float* __restrict__ x, const float* __restrict__ Wg,
                   const float* __restrict__ bias, int* __restrict__ counts,
                   int* __restrict__ tok_list, int* __restrict__ slot_list,
                   float* __restrict__ wt_dense, u16* __restrict__ x_bf, int cap) {
    __shared__ float part[4][16];
    int t = blockIdx.x;
    int tid = threadIdx.x;
    int e = tid & 15;
    int q = tid >> 4;
    const float4* xv = (const float4*)(x + (long)t * H_) + q * 16;
    const float4* wv = (const float4*)(Wg + (long)e * H_) + q * 16;
    float d = 0.f;
#pragma unroll
    for (int i = 0; i < 16; i++) {
        float4 a = xv[i], b = wv[i];
        d += a.x * b.x + a.y * b.y + a.z * b.z + a.w * b.w;
    }
    d += __shfl_down(d, 16);
    d += __shfl_down(d, 32);
    if ((tid & 63) < 16) part[tid >> 6][e] = d;
    {   // fused x -> bf16 (row is cache-hot)
        float4 v = ((const float4*)(x + (long)t * H_))[tid];
        ushort4 o;
        o.x = f2bf(v.x); o.y = f2bf(v.y); o.z = f2bf(v.z); o.w = f2bf(v.w);
        ((ushort4*)(x_bf + (long)t * H_))[tid] = o;
    }
    __syncthreads();
    if (tid >= 64) return;
    int lane = tid;
    float lg = part[0][e] + part[1][e] + part[2][e] + part[3][e];
    float sp = fmaxf(lg, 0.f) + log1pf(expf(-fabsf(lg)));  // stable softplus
    float s = sqrtf(sp);
    float bs = s + bias[e];
    int sel[KSEL]; float ssel[KSEL]; float wsum = 0.f;
#pragma unroll
    for (int k = 0; k < KSEL; k++) {
        float mv = bs; int me = e;
#pragma unroll
        for (int off = 1; off < 16; off <<= 1) {
            float ov = __shfl_xor(mv, off);
            int oe = __shfl_xor(me, off);
            if (ov > mv || (ov == mv && oe < me)) { mv = ov; me = oe; }
        }
        sel[k] = me;
        float sk = __shfl(s, (lane & 48) | me);
        ssel[k] = sk; wsum += sk;
        if (e == me) bs = -1e30f;
    }
    float inv = 2.5f / wsum;
    if (lane < KSEL) {
        int k = lane;
        int se = sel[k];
        wt_dense[t * KSEL + k] = ssel[k] * inv;
        int pos = atomicAdd(&counts[se], 1);
        if (pos < cap) {
            tok_list[se * T_ + pos] = t;
            slot_list[se * T_ + pos] = t * KSEL + k;
        }
    }
}

// ---- transpose+convert: in fp32 [nE][R][C] -> out bf16 [nE][C'][R] ----
// il=1: two sources, columns interleaved by 16-chunks in the output rows:
//   out row for s0 col c = (c>>4)*32 + (c&15); for s1 col c = same + 16.
__global__ __launch_bounds__(256)
void transpose_conv(const float* __restrict__ s0, const float* __restrict__ s1,
                    u16* __restrict__ out, int ldin, int ldout,
                    long sIn, long sOut, int nE, int il) {
    int z = blockIdx.z;
    const float* src; int e, ofs;
    if (il && z >= nE) { src = s1; e = z - nE; ofs = 16; }
    else               { src = s0; e = z;      ofs = 0;  }
    const float* ip = src + (long)e * sIn;
    u16* op = out + (long)e * sOut;
    __shared__ u16 tile[64 * 72];
    int rb = blockIdx.y * 64, cb = blockIdx.x * 64;
    int tid = threadIdx.x;
    int r0 = (tid >> 4) * 4;
    int c4 = (tid & 15) * 4;
#pragma unroll
    for (int i = 0; i < 4; i++) {
        float4 v = *(const float4*)(ip + (long)(rb + r0 + i) * ldin + cb + c4);
        ushort4 o;
        o.x = f2bf(v.x); o.y = f2bf(v.y); o.z = f2bf(v.z); o.w = f2bf(v.w);
        *(ushort4*)&tile[(r0 + i) * 72 + c4] = o;
    }
    __syncthreads();
    int c = tid >> 2;
    int r16 = (tid & 3) * 16;
    short8 a, b;
#pragma unroll
    for (int j = 0; j < 8; j++) {
        a[j] = (short)tile[(r16 + j) * 72 + c];
        b[j] = (short)tile[(r16 + 8 + j) * 72 + c];
    }
    int cg = cb + c;
    int orow = il ? (((cg >> 4) << 5) + (cg & 15) + ofs) : cg;
    u16* orp = op + (long)orow * ldout + rb + r16;
    *(short8*)(orp) = a;
    *(short8*)(orp + 8) = b;
}

// ---------------- segment descriptor for the merged GEMM ----------------
struct Seg {
    const u16* A; const int* gather;
    const u16* Bt;                 // bf16 [N][K], per-expert stride sBe
    void* C; const int* scatter; const int* counts;
    long sAe, sBe, sCe;
    int lda, ldb, ldc;
    int cf32, act, nt, nxt, mt, nE, cap, Mfull;
};

// ---- bf16 GEMM, both operands via global_load_lds, BK=32, double-buffered,
// ---- ONE barrier per K-tile: issue(t+1 -> other buf) before compute(t); the
// ---- barrier's implicit vmcnt(0) drain is covered by ds_reads + 16 MFMAs.
__global__ __launch_bounds__(256)
void moe_gemm(Seg sa, Seg sb) {
    int id = blockIdx.x;
    int n0 = sa.nxt * sa.mt * sa.nE;
    Seg s = (id < n0) ? sa : sb;
    int rid = (id < n0) ? id : id - n0;
    int per = s.nxt * s.mt;
    int e = rid / per;
    int r2 = rid - e * per;
    int my = r2 / s.nxt;
    int nx = r2 - my * s.nxt;
    int Mlim = s.counts ? (s.counts[e] < s.cap ? s.counts[e] : s.cap) : s.Mfull;
    int mbase = my * 128;
    if (mbase >= Mlim) return;
    int nbase = nx * 128;

    __shared__ __align__(16) u16 As[2][128 * 32];   // 2 x 8 KB
    __shared__ __align__(16) u16 Bs[2][128 * 32];   // 2 x 8 KB

    int tid = threadIdx.x, lane = tid & 63, wid = tid >> 6;
    const u16* Abase = s.A + (long)e * s.sAe;
    const u16* Bbase = s.Bt + (long)e * s.sBe;
    const int* gat = s.gather ? s.gather + e * T_ : nullptr;
    const u16 *aptr[2], *bptr[2];
#pragma unroll
    for (int r = 0; r < 2; r++) {
        int chunk = tid + r * 256;
        int row = chunk >> 2, slot = chunk & 3;
        int gr = mbase + row;
        int grc = gr < Mlim ? gr : (Mlim - 1);
        long ar = gat ? (long)gat[grc] : (long)grc;
        aptr[r] = Abase + ar * (long)s.lda + slot * 8;
        bptr[r] = Bbase + (long)(nbase + row) * s.ldb + slot * 8;
    }

    int wm = wid >> 1, wn = wid & 1, lr = lane & 15, lk = lane >> 4;
    f32x4 acc[4][4] = {};
    int nt = s.nt;

    auto issue = [&](int t, int buf) {
        int k0 = t * 32;
        u16* ad = &As[buf][0] + tid * 8;
        u16* bd = &Bs[buf][0] + tid * 8;
        gload16(aptr[0] + k0, ad);
        gload16(aptr[1] + k0, ad + 2048);
        gload16(bptr[0] + k0, bd);
        gload16(bptr[1] + k0, bd + 2048);
    };

    issue(0, 0);
    __syncthreads();   // vmcnt(0): tile 0 landed

    for (int t = 0; t < nt; t++) {
        int cur = t & 1;
        if (t + 1 < nt) issue(t + 1, cur ^ 1);
        const u16* Asc = &As[cur][0];
        const u16* Bsc = &Bs[cur][0];
        short8 afr[4], bfr[4];
#pragma unroll
        for (int mi = 0; mi < 4; mi++)
            afr[mi] = *(const short8*)&Asc[(wm * 64 + mi * 16 + lr) * 32 + lk * 8];
#pragma unroll
        for (int ni = 0; ni < 4; ni++)
            bfr[ni] = *(const short8*)&Bsc[(wn * 64 + ni * 16 + lr) * 32 + lk * 8];
#pragma unroll
        for (int mi = 0; mi < 4; mi++)
#pragma unroll
            for (int ni = 0; ni < 4; ni++)
                acc[mi][ni] = __builtin_amdgcn_mfma_f32_16x16x32_bf16(afr[mi], bfr[ni], acc[mi][ni], 0, 0, 0);
        __syncthreads();   // t+1 landed; all waves done reading buf cur
    }

    // ---- epilogue: C/D layout col = lane&15, row = (lane>>4)*4 + reg ----
    if (s.act == 0) {
        u16* Cb = (u16*)s.C;
        float* Cf = (float*)s.C;
        long cbase = s.scatter ? 0L : (long)e * s.sCe;
        const int* scat = s.scatter ? s.scatter + e * T_ : nullptr;
#pragma unroll
        for (int mi = 0; mi < 4; mi++) {
#pragma unroll
            for (int j = 0; j < 4; j++) {
                int rowt = wm * 64 + mi * 16 + lk * 4 + j;
                int gr = mbase + rowt;
                if (gr >= Mlim) continue;
                long crow = scat ? (long)scat[gr] : (long)gr;
                long rb = cbase + crow * (long)s.ldc;
#pragma unroll
                for (int ni = 0; ni < 4; ni++) {
                    int col = nbase + wn * 64 + ni * 16 + lr;
                    float v = acc[mi][ni][j];
                    if (s.cf32) Cf[rb + col] = v;
                    else        Cb[rb + col] = f2bf(v);
                }
            }
        }
    } else {
        // chunk-16 interleave: gate = acc[mi][2q], up = acc[mi][2q+1] (same lane)
        u16* Co = (u16*)s.C;
        long cbase = (long)e * s.sCe;
#pragma unroll
        for (int mi = 0; mi < 4; mi++) {
#pragma unroll
            for (int j = 0; j < 4; j++) {
                int rowt = wm * 64 + mi * 16 + lk * 4 + j;
                int gr = mbase + rowt;
                if (gr >= Mlim) continue;
                long rb = cbase + (long)gr * s.ldc;
#pragma unroll
                for (int q = 0; q < 2; q++) {
                    int ocol = (nbase >> 1) + wn * 32 + q * 16 + lr;
                    float g = acc[mi][2 * q][j];
                    float u = acc[mi][2 * q + 1][j];
                    float r;
                    if (s.act == 1) {
                        r = g / (1.f + expf(-g)) * u;
                    } else {
                        g = fminf(g, 7.f);
                        u = fminf(fmaxf(u, -7.f), 7.f);
                        r = g / (1.f + expf(-1.702f * g)) * (u + 1.f);
                    }
                    Co[rb + ocol] = f2bf(r);
                }
            }
        }
    }
}

// ---------------- final: out += sum_k w[t][k] * routed(t,k) ----------------
__global__ void final_add_kernel(float* __restrict__ out, const u16* __restrict__ down,
                                 const float* __restrict__ wtd) {
    int i = blockIdx.x * blockDim.x + threadIdx.x;
    int o = i * 4;
    int t = o >> 10;
    int h = o & (H_ - 1);
    float4 w4 = *(const float4*)(wtd + t * 4);
    float wk[4] = {w4.x, w4.y, w4.z, w4.w};
    float4 v = ((float4*)out)[i];
#pragma unroll
    for (int k = 0; k < KSEL; k++) {
        const u16* dr = down + ((long)(t * KSEL + k) << 10) + h;
        ushort4 d4 = *(const ushort4*)dr;
        v.x += wk[k] * bf2f(d4.x);
        v.y += wk[k] * bf2f(d4.y);
        v.z += wk[k] * bf2f(d4.z);
        v.w += wk[k] * bf2f(d4.w);
    }
    ((float4*)out)[i] = v;
}

extern "C" void kernel_launch(void* const* d_in, const int* in_sizes, int n_in,
                              void* d_out, int out_size, void* d_ws, size_t ws_size,
                              hipStream_t stream) {
    const float* x    = (const float*)d_in[0];
    const float* Wg   = (const float*)d_in[2];
    const float* bias = (const float*)d_in[3];
    const float* W1   = (const float*)d_in[4];
    const float* W3   = (const float*)d_in[5];
    const float* W2   = (const float*)d_in[6];
    const float* Wsg  = (const float*)d_in[7];
    const float* Wsu  = (const float*)d_in[8];
    const float* Wsd  = (const float*)d_in[9];
    float* out = (float*)d_out;
    char* ws = (char*)d_ws;

    size_t off = 0;
    auto carve = [&](size_t bytes) -> char* {
        char* p = ws + off;
        off = (off + bytes + 255) & ~(size_t)255;
        return p;
    };
    u16* x_bf   = (u16*)carve((size_t)T_ * H_ * 2);            // 2 MB
    u16* c1     = (u16*)carve((size_t)T_ * IS_ * 2);           // 2 MB
    u16* dwn    = (u16*)carve((size_t)T_ * KSEL * H_ * 2);     // 8 MB
    int* counts    = (int*)carve(E_ * sizeof(int));
    int* tok_list  = (int*)carve((size_t)E_ * T_ * 4);
    int* slot_list = (int*)carve((size_t)E_ * T_ * 4);
    float* wt_dense = (float*)carve((size_t)T_ * KSEL * 4);
    u16* W13t  = (u16*)carve((size_t)E_ * 1024 * 1024 * 2);    // 32 MB  [E][1024n][1024k]
    u16* Wsgut = (u16*)carve((size_t)2048 * 1024 * 2);         // 4 MB   [2048n][1024k]
    u16* W2t   = (u16*)carve((size_t)E_ * 1024 * 512 * 2);     // 16 MB  [E][1024n][512k]
    u16* Wsdt  = (u16*)carve((size_t)1024 * 1024 * 2);         // 2 MB   [1024n][1024k]

    long cap = 768;
    int capB = (int)(cap / 128);
    u16* act = (u16*)carve((size_t)E_ * cap * I_ * 2);         // ~12.6 MB

    hipMemsetAsync(counts, 0, E_ * sizeof(int), stream);
    router_kernel<<<T_, 256, 0, stream>>>(x, Wg, bias, counts, tok_list, slot_list,
                                          wt_dense, x_bf, (int)cap);

    dim3 blk(256);
    // weight transposes (fp32 [K][N] -> bf16 [N][K]); gate/up column-interleaved
    transpose_conv<<<dim3(I_ / 64, H_ / 64, 2 * E_), blk, 0, stream>>>(
        W1, W3, W13t, I_, H_, (long)H_ * I_, (long)1024 * 1024, E_, 1);
    transpose_conv<<<dim3(IS_ / 64, H_ / 64, 2), blk, 0, stream>>>(
        Wsg, Wsu, Wsgut, IS_, H_, 0, 0, 1, 1);
    transpose_conv<<<dim3(H_ / 64, I_ / 64, E_), blk, 0, stream>>>(
        W2, W2, W2t, H_, I_, (long)I_ * H_, (long)H_ * I_, E_, 0);
    transpose_conv<<<dim3(H_ / 64, IS_ / 64, 1), blk, 0, stream>>>(
        Wsd, Wsd, Wsdt, H_, IS_, 0, 0, 1, 0);

    // ---- UP: expert-up (fused clamped-swiglu) + shared-up (fused silu) ----
    Seg eu;
    eu.A = x_bf; eu.gather = tok_list; eu.Bt = W13t;
    eu.C = (void*)act; eu.scatter = nullptr; eu.counts = counts;
    eu.sAe = 0; eu.sBe = (long)1024 * 1024; eu.sCe = (long)cap * I_;
    eu.lda = H_; eu.ldb = H_; eu.ldc = I_;
    eu.cf32 = 0; eu.act = 2; eu.nt = H_ / 32;
    eu.nxt = 8; eu.mt = capB; eu.nE = E_; eu.cap = (int)cap; eu.Mfull = 0;
    Seg su;
    su.A = x_bf; su.gather = nullptr; su.Bt = Wsgut;
    su.C = (void*)c1; su.scatter = nullptr; su.counts = nullptr;
    su.sAe = 0; su.sBe = 0; su.sCe = 0;
    su.lda = H_; su.ldb = H_; su.ldc = IS_;
    su.cf32 = 0; su.act = 1; su.nt = H_ / 32;
    su.nxt = 16; su.mt = 8; su.nE = 1; su.cap = 0; su.Mfull = T_;
    int upBlocks = eu.nxt * eu.mt * eu.nE + su.nxt * su.mt * su.nE;
    moe_gemm<<<upBlocks, blk, 0, stream>>>(eu, su);

    // ---- DOWN: expert-down (scatter, bf16) + shared-down (fp32 -> out) ----
    Seg ed;
    ed.A = act; ed.gather = nullptr; ed.Bt = W2t;
    ed.C = (void*)dwn; ed.scatter = slot_list; ed.counts = counts;
    ed.sAe = (long)cap * I_; ed.sBe = (long)H_ * I_; ed.sCe = 0;
    ed.lda = I_; ed.ldb = I_; ed.ldc = H_;
    ed.cf32 = 0; ed.act = 0; ed.nt = I_ / 32;
    ed.nxt = 8; ed.mt = capB; ed.nE = E_; ed.cap = (int)cap; ed.Mfull = 0;
    Seg sd;
    sd.A = c1; sd.gather = nullptr; sd.Bt = Wsdt;
    sd.C = (void*)out; sd.scatter = nullptr; sd.counts = nullptr;
    sd.sAe = 0; sd.sBe = 0; sd.sCe = 0;
    sd.lda = IS_; sd.ldb = IS_; sd.ldc = H_;
    sd.cf32 = 1; sd.act = 0; sd.nt = IS_ / 32;
    sd.nxt = 8; sd.mt = 8; sd.nE = 1; sd.cap = 0; sd.Mfull = T_;
    int dnBlocks = ed.nxt * ed.mt * ed.nE + sd.nxt * sd.mt * sd.nE;
    moe_gemm<<<dnBlocks, blk, 0, stream>>>(ed, sd);

    final_add_kernel<<<T_ * H_ / 4 / 256, 256, 0, stream>>>(out, dwn, wt_dense);
}

// Round 11
// 90.679 us; speedup vs baseline: 1.4089x; 1.4089x over previous
//
#include <hip/hip_runtime.h>
#include <hip/hip_bf16.h>
#include <math.h>

#define T_ 1024
#define H_ 1024
#define E_ 16
#define I_ 512
#define KSEL 4
#define IS_ 1024

typedef unsigned short u16;
typedef __attribute__((ext_vector_type(8))) short short8;
typedef __attribute__((ext_vector_type(4))) float f32x4;

__device__ __forceinline__ u16 f2bf(float f) {
    union { float f; unsigned int u; } v; v.f = f;
    unsigned int u = v.u;
    return (u16)((u + 0x7fffu + ((u >> 16) & 1u)) >> 16);
}
__device__ __forceinline__ float bf2f(u16 b) {
    union { unsigned int u; float f; } v; v.u = ((unsigned int)b) << 16;
    return v.f;
}
__device__ __forceinline__ unsigned cvtpk(float lo, float hi) {
    unsigned r;
    asm("v_cvt_pk_bf16_f32 %0, %1, %2" : "=v"(r) : "v"(lo), "v"(hi));
    return r;
}
__device__ __forceinline__ void gload16(const u16* g, u16* l) {
    __builtin_amdgcn_global_load_lds(
        (const __attribute__((address_space(1))) void*)g,
        (__attribute__((address_space(3))) void*)l, 16, 0, 0);
}
__device__ __forceinline__ void SB0() { __builtin_amdgcn_sched_barrier(0); }
__device__ __forceinline__ void BARRIER() {
    asm volatile("s_waitcnt lgkmcnt(0)" ::: "memory");
    __builtin_amdgcn_s_barrier();
    __builtin_amdgcn_sched_barrier(0);
}

// ------ router: 1 block/token; emits x_bf row, per-expert lists, dense weights ------
__global__ __launch_bounds__(256)
void router_kernel(const float* __restrict__ x, const float* __restrict__ Wg,
                   const float* __restrict__ bias, int* __restrict__ counts,
                   int* __restrict__ tok_list, int* __restrict__ slot_list,
                   float* __restrict__ wt_dense, u16* __restrict__ x_bf, int cap) {
    __shared__ float part[4][16];
    int t = blockIdx.x;
    int tid = threadIdx.x;
    int e = tid & 15;
    int q = tid >> 4;
    const float4* xv = (const float4*)(x + (long)t * H_) + q * 16;
    const float4* wv = (const float4*)(Wg + (long)e * H_) + q * 16;
    float d = 0.f;
#pragma unroll
    for (int i = 0; i < 16; i++) {
        float4 a = xv[i], b = wv[i];
        d += a.x * b.x + a.y * b.y + a.z * b.z + a.w * b.w;
    }
    d += __shfl_down(d, 16);
    d += __shfl_down(d, 32);
    if ((tid & 63) < 16) part[tid >> 6][e] = d;
    {   // fused x -> bf16 (row is cache-hot)
        float4 v = ((const float4*)(x + (long)t * H_))[tid];
        ushort4 o;
        o.x = f2bf(v.x); o.y = f2bf(v.y); o.z = f2bf(v.z); o.w = f2bf(v.w);
        ((ushort4*)(x_bf + (long)t * H_))[tid] = o;
    }
    __syncthreads();
    if (tid >= 64) return;
    int lane = tid;
    float lg = part[0][e] + part[1][e] + part[2][e] + part[3][e];
    float sp = fmaxf(lg, 0.f) + log1pf(expf(-fabsf(lg)));  // stable softplus
    float s = sqrtf(sp);
    float bs = s + bias[e];
    int sel[KSEL]; float ssel[KSEL]; float wsum = 0.f;
#pragma unroll
    for (int k = 0; k < KSEL; k++) {
        float mv = bs; int me = e;
#pragma unroll
        for (int off = 1; off < 16; off <<= 1) {
            float ov = __shfl_xor(mv, off);
            int oe = __shfl_xor(me, off);
            if (ov > mv || (ov == mv && oe < me)) { mv = ov; me = oe; }
        }
        sel[k] = me;
        float sk = __shfl(s, (lane & 48) | me);
        ssel[k] = sk; wsum += sk;
        if (e == me) bs = -1e30f;
    }
    float inv = 2.5f / wsum;
    if (lane < KSEL) {
        int k = lane;
        int se = sel[k];
        wt_dense[t * KSEL + k] = ssel[k] * inv;
        int pos = atomicAdd(&counts[se], 1);
        if (pos < cap) {
            tok_list[se * T_ + pos] = t;
            slot_list[se * T_ + pos] = t * KSEL + k;
        }
    }
}

// ---------------- segment descriptor for the merged GEMM ----------------
struct Seg {
    const u16* A; const int* gather;
    const float* B0; const float* B1;
    void* C; const int* scatter; const int* counts;
    long sAe, sBe, sCe;
    int lda, ldb, ldc;
    int il, cf32, act, nt, nxt, mt, nE, cap, Mfull;
};

// ---- deep-pipelined bf16 GEMM: A(bf16) via global_load_lds (2-ahead, 3 bufs),
// ---- B(fp32) float4 reg-stage + cvt_pk + PERMUTED-ROW swizzled b128 ds_write.
// ---- LDS B layout: col n stored at row rho(n)=((n&3)<<5)|(n>>2); granule g at
// ---- slot g ^ key(rho), key(rho) = (rho&7) ^ P[rho>>5], P={0,5,2,7}.
// ---- Both ds_write_b128 (8 lanes/bank-group) and ds_read_b128 at the floor.
// ---- No vmcnt(0) in the loop: barrier = lgkmcnt(0)+s_barrier only.
__global__ __launch_bounds__(256, 2)
void moe_gemm(Seg sa, Seg sb) {
    int id = blockIdx.x;
    int n0 = sa.nxt * sa.mt * sa.nE;
    Seg s = (id < n0) ? sa : sb;
    int rid = (id < n0) ? id : id - n0;
    int per = s.nxt * s.mt;
    int e = rid / per;
    int r2 = rid - e * per;
    int my = r2 / s.nxt;
    int nx = r2 - my * s.nxt;
    int Mlim = s.counts ? (s.counts[e] < s.cap ? s.counts[e] : s.cap) : s.Mfull;
    int mbase = my * 128;
    if (mbase >= Mlim) return;
    int nbase = nx * 128;
    int nt = s.nt;

    __shared__ __align__(16) u16 lds[40960];   // 80 KB: 3 A-bufs + 2 B-bufs (16KB each)
    u16* a0 = lds;
    u16* a1 = lds + 8192;
    u16* a2 = lds + 16384;
    u16* Bb0 = lds + 24576;
    u16* Bb1 = lds + 32768;

    int tid = threadIdx.x, lane = tid & 63, wid = tid >> 6;

    // ---- A staging: dest row = tid>>3 + j*32, slot = tid&7; src kc = slot^(row&7) ----
    const u16* Abase = s.A + (long)e * s.sAe;
    const int* gat = s.gather ? s.gather + e * T_ : nullptr;
    const u16* aptr[4];
    {
        int srow = tid >> 3;
        int kca = (tid & 7) ^ (srow & 7);
#pragma unroll
        for (int j = 0; j < 4; j++) {
            int gr = mbase + srow + j * 32;
            int grc = gr < Mlim ? gr : (Mlim - 1);
            long ar = gat ? (long)gat[grc] : (long)grc;
            aptr[j] = Abase + ar * (long)s.lda + kca * 8;
        }
    }
    int adoff = tid * 8;

    // ---- B staging: thread owns 4 phys cols (cg*4..+3) x 8 k-rows (kc*8..+7) ----
    int cg = tid & 31, kc = tid >> 5;
    const float* bp;
    {
        int pc = nbase + cg * 4;
        if (s.il) {
            int chunk = pc >> 4;
            const float* src = (chunk & 1) ? s.B1 : s.B0;
            bp = src + (long)e * s.sBe + ((chunk >> 1) * 16 + (pc & 15));
        } else {
            bp = s.B0 + (long)e * s.sBe + pc;
        }
        bp += (long)(kc * 8) * s.ldb;
    }
    long ldbl = s.ldb;
    f32x4 bA[8], bB[8];

    auto issueA = [&](u16* ab, int kt) {
#pragma unroll
        for (int j = 0; j < 4; j++)
            gload16(aptr[j] + kt * 64, ab + adoff + j * 2048);
    };
    auto issueB = [&](f32x4 (&b)[8], int kt) {
        const float* r = bp + (long)(kt * 64) * ldbl;
#pragma unroll
        for (int i = 0; i < 8; i++)
            b[i] = *(const f32x4*)(r + (long)i * ldbl);
    };
    // permuted-row conflict-free write: col n=4cg+j -> rho=(j<<5)|cg,
    // slot = kc ^ (cg&7) ^ P[j]
    auto cvtw = [&](f32x4 (&b)[8], u16* bb) {
        const int P[4] = {0, 5, 2, 7};
#pragma unroll
        for (int j = 0; j < 4; j++) {
            int rho = (j << 5) | cg;
            int slot = kc ^ (cg & 7) ^ P[j];
            uint4 v;
            v.x = cvtpk(b[0][j], b[1][j]);
            v.y = cvtpk(b[2][j], b[3][j]);
            v.z = cvtpk(b[4][j], b[5][j]);
            v.w = cvtpk(b[6][j], b[7][j]);
            *(uint4*)(bb + rho * 64 + slot * 8) = v;
        }
    };

    int wm = wid >> 1, wn = wid & 1, lr = lane & 15, lk = lane >> 4;
    f32x4 acc[4][4] = {};
    auto compute = [&](const u16* ab, const u16* bb) {
        const int P[4] = {0, 5, 2, 7};
#pragma unroll
        for (int kk = 0; kk < 2; kk++) {
            short8 afr[4], bfr[4];
#pragma unroll
            for (int mi = 0; mi < 4; mi++) {
                int R = wm * 64 + mi * 16 + lr;
                afr[mi] = *(const short8*)(ab + R * 64 + (((kk * 4 + lk) ^ (R & 7)) << 3));
            }
#pragma unroll
            for (int ni = 0; ni < 4; ni++) {
                int R = wn * 64 + ni * 16 + lr;
                int rho = ((R & 3) << 5) | (R >> 2);
                int key = ((R >> 2) & 7) ^ P[R & 3];
                bfr[ni] = *(const short8*)(bb + rho * 64 + (((kk * 4 + lk) ^ key) << 3));
            }
            __builtin_amdgcn_s_setprio(1);
#pragma unroll
            for (int mi = 0; mi < 4; mi++)
#pragma unroll
                for (int ni = 0; ni < 4; ni++)
                    acc[mi][ni] = __builtin_amdgcn_mfma_f32_16x16x32_bf16(afr[mi], bfr[ni], acc[mi][ni], 0, 0, 0);
            __builtin_amdgcn_s_setprio(0);
        }
    };

    // ---- prologue: tiles 0,1 in flight; A issued BEFORE B each step so the
    // ---- compiler's reg-dep wait on B retires the matching A gloads (vmcnt FIFO).
    issueA(a0, 0); SB0(); issueB(bA, 0); SB0();
    issueA(a1, 1); SB0(); issueB(bB, 1); SB0();
    cvtw(bA, Bb0);           // waits B(0) -> A(0) retired too
    BARRIER();

    for (int t = 0; t < nt; t += 2) {
        // even tile t
        if (t + 2 < nt) { issueA(a2, t + 2); SB0(); issueB(bA, t + 2); SB0(); }
        compute(a0, Bb0);
        cvtw(bB, Bb1);       // tile t+1; waits B(t+1) -> A(t+1) retired
        BARRIER();
        // odd tile t+1
        if (t + 3 < nt) { issueA(a0, t + 3); SB0(); issueB(bB, t + 3); SB0(); }
        compute(a1, Bb1);
        if (t + 2 < nt) { cvtw(bA, Bb0); BARRIER(); }
        u16* tmp = a0; a0 = a2; a2 = a1; a1 = tmp;
    }

    // ---- epilogue: C/D layout col = lane&15, row = (lane>>4)*4 + reg ----
    if (s.act == 0) {
        u16* Cb = (u16*)s.C;
        float* Cf = (float*)s.C;
        long cbase = s.scatter ? 0L : (long)e * s.sCe;
        const int* scat = s.scatter ? s.scatter + e * T_ : nullptr;
#pragma unroll
        for (int mi = 0; mi < 4; mi++) {
#pragma unroll
            for (int j = 0; j < 4; j++) {
                int rowt = wm * 64 + mi * 16 + lk * 4 + j;
                int gr = mbase + rowt;
                if (gr >= Mlim) continue;
                long crow = scat ? (long)scat[gr] : (long)gr;
                long rb = cbase + crow * (long)s.ldc;
#pragma unroll
                for (int ni = 0; ni < 4; ni++) {
                    int col = nbase + wn * 64 + ni * 16 + lr;
                    float v = acc[mi][ni][j];
                    if (s.cf32) Cf[rb + col] = v;
                    else        Cb[rb + col] = f2bf(v);
                }
            }
        }
    } else {
        // chunk-16 pairing: gate = acc[mi][2q], up = acc[mi][2q+1] (same lane)
        u16* Co = (u16*)s.C;
        long cbase = (long)e * s.sCe;
#pragma unroll
        for (int mi = 0; mi < 4; mi++) {
#pragma unroll
            for (int j = 0; j < 4; j++) {
                int rowt = wm * 64 + mi * 16 + lk * 4 + j;
                int gr = mbase + rowt;
                if (gr >= Mlim) continue;
                long rb = cbase + (long)gr * s.ldc;
#pragma unroll
                for (int q = 0; q < 2; q++) {
                    int ocol = (nbase >> 1) + wn * 32 + q * 16 + lr;
                    float g = acc[mi][2 * q][j];
                    float u = acc[mi][2 * q + 1][j];
                    float r;
                    if (s.act == 1) {
                        r = g / (1.f + expf(-g)) * u;
                    } else {
                        g = fminf(g, 7.f);
                        u = fminf(fmaxf(u, -7.f), 7.f);
                        r = g / (1.f + expf(-1.702f * g)) * (u + 1.f);
                    }
                    Co[rb + ocol] = f2bf(r);
                }
            }
        }
    }
}

// ---------------- final: out += sum_k w[t][k] * routed(t,k) ----------------
__global__ void final_add_kernel(float* __restrict__ out, const u16* __restrict__ down,
                                 const float* __restrict__ wtd) {
    int i = blockIdx.x * blockDim.x + threadIdx.x;
    int o = i * 4;
    int t = o >> 10;
    int h = o & (H_ - 1);
    float4 w4 = *(const float4*)(wtd + t * 4);
    float wk[4] = {w4.x, w4.y, w4.z, w4.w};
    float4 v = ((float4*)out)[i];
#pragma unroll
    for (int k = 0; k < KSEL; k++) {
        const u16* dr = down + ((long)(t * KSEL + k) << 10) + h;
        ushort4 d4 = *(const ushort4*)dr;
        v.x += wk[k] * bf2f(d4.x);
        v.y += wk[k] * bf2f(d4.y);
        v.z += wk[k] * bf2f(d4.z);
        v.w += wk[k] * bf2f(d4.w);
    }
    ((float4*)out)[i] = v;
}

extern "C" void kernel_launch(void* const* d_in, const int* in_sizes, int n_in,
                              void* d_out, int out_size, void* d_ws, size_t ws_size,
                              hipStream_t stream) {
    const float* x    = (const float*)d_in[0];
    const float* Wg   = (const float*)d_in[2];
    const float* bias = (const float*)d_in[3];
    const float* W1   = (const float*)d_in[4];
    const float* W3   = (const float*)d_in[5];
    const float* W2   = (const float*)d_in[6];
    const float* Wsg  = (const float*)d_in[7];
    const float* Wsu  = (const float*)d_in[8];
    const float* Wsd  = (const float*)d_in[9];
    float* out = (float*)d_out;
    char* ws = (char*)d_ws;

    size_t off = 0;
    auto carve = [&](size_t bytes) -> char* {
        char* p = ws + off;
        off = (off + bytes + 255) & ~(size_t)255;
        return p;
    };
    u16* x_bf   = (u16*)carve((size_t)T_ * H_ * 2);            // 2 MB
    u16* c1     = (u16*)carve((size_t)T_ * IS_ * 2);           // 2 MB
    u16* dwn    = (u16*)carve((size_t)T_ * KSEL * H_ * 2);     // 8 MB
    int* counts    = (int*)carve(E_ * sizeof(int));
    int* tok_list  = (int*)carve((size_t)E_ * T_ * 4);
    int* slot_list = (int*)carve((size_t)E_ * T_ * 4);
    float* wt_dense = (float*)carve((size_t)T_ * KSEL * 4);

    long cap = 768;
    int capB = (int)(cap / 128);
    u16* act = (u16*)carve((size_t)E_ * cap * I_ * 2);         // ~12.6 MB

    hipMemsetAsync(counts, 0, E_ * sizeof(int), stream);
    router_kernel<<<T_, 256, 0, stream>>>(x, Wg, bias, counts, tok_list, slot_list,
                                          wt_dense, x_bf, (int)cap);

    // ---- UP: expert-up (fused clamped-swiglu) + shared-up (fused silu), one launch ----
    Seg eu;
    eu.A = x_bf; eu.gather = tok_list; eu.B0 = W1; eu.B1 = W3;
    eu.C = (void*)act; eu.scatter = nullptr; eu.counts = counts;
    eu.sAe = 0; eu.sBe = (long)H_ * I_; eu.sCe = (long)cap * I_;
    eu.lda = H_; eu.ldb = I_; eu.ldc = I_;
    eu.il = 1; eu.cf32 = 0; eu.act = 2; eu.nt = 16;
    eu.nxt = 8; eu.mt = capB; eu.nE = E_; eu.cap = (int)cap; eu.Mfull = 0;
    Seg su;
    su.A = x_bf; su.gather = nullptr; su.B0 = Wsg; su.B1 = Wsu;
    su.C = (void*)c1; su.scatter = nullptr; su.counts = nullptr;
    su.sAe = 0; su.sBe = 0; su.sCe = 0;
    su.lda = H_; su.ldb = IS_; su.ldc = IS_;
    su.il = 1; su.cf32 = 0; su.act = 1; su.nt = 16;
    su.nxt = 16; su.mt = 8; su.nE = 1; su.cap = 0; su.Mfull = T_;
    int upBlocks = eu.nxt * eu.mt * eu.nE + su.nxt * su.mt * su.nE;
    moe_gemm<<<upBlocks, 256, 0, stream>>>(eu, su);

    // ---- DOWN: expert-down (scatter, bf16) + shared-down (fp32 -> out), one launch ----
    Seg ed;
    ed.A = act; ed.gather = nullptr; ed.B0 = W2; ed.B1 = W2;
    ed.C = (void*)dwn; ed.scatter = slot_list; ed.counts = counts;
    ed.sAe = (long)cap * I_; ed.sBe = (long)I_ * H_; ed.sCe = 0;
    ed.lda = I_; ed.ldb = H_; ed.ldc = H_;
    ed.il = 0; ed.cf32 = 0; ed.act = 0; ed.nt = 8;
    ed.nxt = 8; ed.mt = capB; ed.nE = E_; ed.cap = (int)cap; ed.Mfull = 0;
    Seg sd;
    sd.A = c1; sd.gather = nullptr; sd.B0 = Wsd; sd.B1 = Wsd;
    sd.C = (void*)out; sd.scatter = nullptr; sd.counts = nullptr;
    sd.sAe = 0; sd.sBe = 0; sd.sCe = 0;
    sd.lda = IS_; sd.ldb = H_; sd.ldc = H_;
    sd.il = 0; sd.cf32 = 1; sd.act = 0; sd.nt = 16;
    sd.nxt = 8; sd.mt = 8; sd.nE = 1; sd.cap = 0; sd.Mfull = T_;
    int dnBlocks = ed.nxt * ed.mt * ed.nE + sd.nxt * sd.mt * sd.nE;
    moe_gemm<<<dnBlocks, 256, 0, stream>>>(ed, sd);

    final_add_kernel<<<T_ * H_ / 4 / 256, 256, 0, stream>>>(out, dwn, wt_dense);
}